// Round 4
// baseline (212.566 us; speedup 1.0000x reference)
//
#include <hip/hip_runtime.h>
#include <math.h>

#ifndef M_PI
#define M_PI 3.14159265358979323846
#endif

// JPEG base quantization tables (values are exact integers)
static __device__ const double LUM_BASE[64] = {
 16,11,10,16,24,40,51,61,
 12,12,14,19,26,58,60,55,
 14,13,16,24,40,57,69,56,
 14,17,22,29,51,87,80,62,
 18,22,37,56,68,109,103,77,
 24,35,55,64,81,104,113,92,
 49,64,78,87,103,121,120,101,
 72,92,95,98,112,100,103,99};
static __device__ const double CHROM_BASE[64] = {
 17,18,24,47,99,99,99,99,
 18,21,26,66,99,99,99,99,
 24,26,56,99,99,99,99,99,
 47,66,99,99,99,99,99,99,
 99,99,99,99,99,99,99,99,
 99,99,99,99,99,99,99,99,
 99,99,99,99,99,99,99,99,
 99,99,99,99,99,99,99,99};

// One thread = one ROW of one 8x8 block of one channel (8 f64 in registers).
// Workgroup = 192 threads = 3 waves; wave w = channel w, covering an
// 8-row x 64-col strip (8 blocks). Separable DCT via register row-matmuls
// with LDS 8x8 transposes between passes (pad-9/stride-72 layout = b64 floor,
// no excess bank conflicts). Grid = 16 images x 64 rowstrips x 8 colstrips.
__global__ __launch_bounds__(192, 4) void jpeg_fwd(const float* __restrict__ img,
                                                   const int* __restrict__ quality,
                                                   float* __restrict__ out)
{
    __shared__ double Md[64];          // DCT matrix, f64 (device cos, as passing rounds)
    __shared__ double QT[128];         // [2][8][8] scaled quant tables, f64
    __shared__ double TR[3][576];      // per-wave transpose buf: elem (r,k) of blk at blk*72+r*9+k
    __shared__ float  REC[3][8][68];   // reconstructed YCbCr strip (f32), row pad 68

    const int t = threadIdx.x;

    if (t < 64) {
        int k = t >> 3, n = t & 7;
        double norm = (k == 0) ? sqrt(1.0 / 8.0) : sqrt(2.0 / 8.0);
        Md[t] = norm * cos(M_PI / 8.0 * ((double)n + 0.5) * (double)k);
    } else {
        int qi  = t - 64;                 // 0..127
        int tbl = qi >> 6, e = qi & 63;
        int q   = quality[0];
        q = q < 1 ? 1 : (q > 100 ? 100 : q);
        double scale = (q < 50) ? (5000.0 / (double)q) : (200.0 - 2.0 * (double)q);
        double base  = tbl ? CHROM_BASE[e] : LUM_BASE[e];
        double v = (base * scale + 50.0) / 100.0;
        QT[qi] = fmin(fmax(v, 1.0), 255.0);
    }
    __syncthreads();

    const int w   = t >> 6;      // channel = wave id (wave-uniform)
    const int l   = t & 63;
    const int blk = l >> 3;      // block within strip (0..7)
    const int rr  = l & 7;       // row within block

    const int b    = blockIdx.x >> 9;   // image index
    const int rem  = blockIdx.x & 511;
    const int row0 = (rem >> 3) << 3;   // strip row * 8
    const int col0 = (rem & 7) << 6;    // strip col * 64

    const size_t plane = 512 * 512;

    // Exact f64 YCbCr weights (same expressions as the passing round-2 kernel)
    const double W00 =  0.299,   W01 =  0.587,   W02 =  0.114;
    const double W10 = -0.1687,  W11 = -0.3313,  W12 =  0.5;
    const double W20 =  0.5,     W21 = -0.4187,  W22 = -0.0813;

    // ---- Load my row's 8 pixels, all 3 planes (float4-coalesced 32B chunks)
    const float* p = img + (size_t)(b * 3) * plane + (size_t)(row0 + rr) * 512 + col0 + blk * 8;
    float4 R0 = *(const float4*)(p);
    float4 R1 = *(const float4*)(p + 4);
    float4 G0 = *(const float4*)(p + plane);
    float4 G1 = *(const float4*)(p + plane + 4);
    float4 B0 = *(const float4*)(p + 2 * plane);
    float4 B1 = *(const float4*)(p + 2 * plane + 4);
    float rf[8] = {R0.x, R0.y, R0.z, R0.w, R1.x, R1.y, R1.z, R1.w};
    float gf[8] = {G0.x, G0.y, G0.z, G0.w, G1.x, G1.y, G1.z, G1.w};
    float bf[8] = {B0.x, B0.y, B0.z, B0.w, B1.x, B1.y, B1.z, B1.w};

    // ---- Color convert (my channel only), -128  [identical f64 exprs to R2]
    double row[8];
    #pragma unroll
    for (int k = 0; k < 8; ++k) {
        double rv = (double)rf[k] * 255.0;
        double gv = (double)gf[k] * 255.0;
        double bv = (double)bf[k] * 255.0;
        double v;
        if (w == 0)      v = W00 * rv + W01 * gv + W02 * bv;
        else if (w == 1) v = W10 * rv + W11 * gv + W12 * bv + 128.0;
        else             v = W20 * rv + W21 * gv + W22 * bv + 128.0;
        row[k] = v - 128.0;
    }

    // ---- P1: row @ M^T  (A1 = Xc M^T, row rr)   [same products+order as R2 ph2]
    double y[8];
    #pragma unroll
    for (int c = 0; c < 8; ++c) {
        double s = 0.0;
        #pragma unroll
        for (int k = 0; k < 8; ++k)
            s += row[k] * Md[(c << 3) + k];
        y[c] = s;
    }

    // ---- Transpose 1 (write rows, read columns)
    {
        double* tb = TR[w];
        int wbase = blk * 72 + rr * 9;
        #pragma unroll
        for (int k = 0; k < 8; ++k) tb[wbase + k] = y[k];
    }
    __syncthreads();
    double t1[8];
    {
        const double* tb = TR[w];
        int rbase = blk * 72 + rr;
        #pragma unroll
        for (int k = 0; k < 8; ++k) t1[k] = tb[rbase + k * 9];
    }

    // ---- P2: (A1^T row) @ M^T  -> dct^T row rr   [same products+order as R2 ph3]
    // ---- + quantize: tq = rint(dct/q)*q          [identical to R2]
    const int sel = ((b * 3 + w) < 16) ? 0 : 1;
    double wq[8];
    #pragma unroll
    for (int j = 0; j < 8; ++j) {
        double s = 0.0;
        #pragma unroll
        for (int k = 0; k < 8; ++k)
            s += t1[k] * Md[(j << 3) + k];
        double q = QT[(sel << 6) + (j << 3) + rr];
        wq[j] = rint(s / q) * q;     // round half-to-even, like jnp.round
    }

    // ---- P3: (tq^T row) @ M   (A3 = tq^T M, row rr)  [post-cliff; reassoc ok]
    double a3[8];
    #pragma unroll
    for (int j = 0; j < 8; ++j) {
        double s = 0.0;
        #pragma unroll
        for (int k = 0; k < 8; ++k)
            s += wq[k] * Md[(k << 3) + j];
        a3[j] = s;
    }

    // ---- Transpose 2
    __syncthreads();   // protect T1 reads before buffer reuse
    {
        double* tb = TR[w];
        int wbase = blk * 72 + rr * 9;
        #pragma unroll
        for (int k = 0; k < 8; ++k) tb[wbase + k] = a3[k];
    }
    __syncthreads();
    double t2[8];
    {
        const double* tb = TR[w];
        int rbase = blk * 72 + rr;
        #pragma unroll
        for (int k = 0; k < 8; ++k) t2[k] = tb[rbase + k * 9];
    }

    // ---- P4: (A3^T row) @ M  + 128 -> idct row rr
    #pragma unroll
    for (int i = 0; i < 8; ++i) {
        double s = 0.0;
        #pragma unroll
        for (int k = 0; k < 8; ++k)
            s += t2[k] * Md[(k << 3) + i];
        double o = s + 128.0;
        REC[w][rr][blk * 8 + i] = (float)o;   // f32 staging (smooth region)
    }
    __syncthreads();

    // ---- Color back (my wave writes plane w), /255, clip, coalesced store
    float* q0 = out + (size_t)(b * 3 + w) * plane + (size_t)(row0 + rr) * 512 + col0 + blk * 8;
    float o[8];
    #pragma unroll
    for (int k = 0; k < 8; ++k) {
        double yv = (double)REC[0][rr][blk * 8 + k];
        double cb = (double)REC[1][rr][blk * 8 + k] - 128.0;
        double cr = (double)REC[2][rr][blk * 8 + k] - 128.0;
        double v;
        if (w == 0)      v = yv + 1.402 * cr;
        else if (w == 1) v = yv - 0.34414 * cb - 0.71414 * cr;
        else             v = yv + 1.772 * cb;
        o[k] = (float)fmin(fmax(v / 255.0, 0.0), 1.0);
    }
    *(float4*)(q0)     = make_float4(o[0], o[1], o[2], o[3]);
    *(float4*)(q0 + 4) = make_float4(o[4], o[5], o[6], o[7]);
}

extern "C" void kernel_launch(void* const* d_in, const int* in_sizes, int n_in,
                              void* d_out, int out_size, void* d_ws, size_t ws_size,
                              hipStream_t stream) {
    const float* img     = (const float*)d_in[0];
    const int*   quality = (const int*)d_in[1];
    float*       out     = (float*)d_out;
    // 16 images x 64 row-strips x 8 col-strips = 8192 workgroups x 192 threads
    jpeg_fwd<<<8192, 192, 0, stream>>>(img, quality, out);
}

// Round 5
// 125.308 us; speedup vs baseline: 1.6964x; 1.6964x over previous
//
#include <hip/hip_runtime.h>
#include <math.h>

// Correctly-rounded double constants: Cj = cos(j*pi/16), N0 = sqrt(1/8).
#define C1 0.9807852804032304
#define C2 0.9238795325112867
#define C3 0.8314696123025452
#define C4 0.7071067811865476
#define C5 0.5555702330196022
#define C6 0.3826834323650898
#define C7 0.19509032201612825
#define N0 0.35355339059327373

// DCT-II matrix M[k][n] = norm_k * cos(pi/8*(n+0.5)*k), fully compile-time.
// (norm_k = 0.5 exactly for k>0, so entries are exact halvings of Cj.)
static constexpr double Mc[8][8] = {
 {  N0,      N0,      N0,      N0,      N0,      N0,      N0,      N0    },
 {  .5*C1,   .5*C3,   .5*C5,   .5*C7,  -.5*C7,  -.5*C5,  -.5*C3,  -.5*C1 },
 {  .5*C2,   .5*C6,  -.5*C6,  -.5*C2,  -.5*C2,  -.5*C6,   .5*C6,   .5*C2 },
 {  .5*C3,  -.5*C7,  -.5*C1,  -.5*C5,   .5*C5,   .5*C1,   .5*C7,  -.5*C3 },
 {  .5*C4,  -.5*C4,  -.5*C4,   .5*C4,   .5*C4,  -.5*C4,  -.5*C4,   .5*C4 },
 {  .5*C5,  -.5*C1,   .5*C7,   .5*C3,  -.5*C3,  -.5*C7,   .5*C1,  -.5*C5 },
 {  .5*C6,  -.5*C2,   .5*C2,  -.5*C6,  -.5*C6,   .5*C2,  -.5*C2,   .5*C6 },
 {  .5*C7,  -.5*C5,   .5*C3,  -.5*C1,   .5*C1,  -.5*C3,   .5*C5,  -.5*C7 },
};

// JPEG base quantization tables (exact integers)
static __device__ const double LUM_BASE[64] = {
 16,11,10,16,24,40,51,61,
 12,12,14,19,26,58,60,55,
 14,13,16,24,40,57,69,56,
 14,17,22,29,51,87,80,62,
 18,22,37,56,68,109,103,77,
 24,35,55,64,81,104,113,92,
 49,64,78,87,103,121,120,101,
 72,92,95,98,112,100,103,99};
static __device__ const double CHROM_BASE[64] = {
 17,18,24,47,99,99,99,99,
 18,21,26,66,99,99,99,99,
 24,26,56,99,99,99,99,99,
 47,66,99,99,99,99,99,99,
 99,99,99,99,99,99,99,99,
 99,99,99,99,99,99,99,99,
 99,99,99,99,99,99,99,99,
 99,99,99,99,99,99,99,99};

// One thread = one ROW of one 8x8 block of one channel (8 f64 in registers).
// Workgroup = 192 threads = 3 waves; wave w = channel w of an 8x64 strip
// (8 blocks). DCT matrix is compile-time constant -> zero LDS reads for M.
// Transposes via pad-9 b64 LDS layout (bank-floor, no excess conflicts).
__global__ __launch_bounds__(192, 2) void jpeg_fwd(const float* __restrict__ img,
                                                   const int* __restrict__ quality,
                                                   float* __restrict__ out)
{
    __shared__ double QT[128];         // [2][8][8] scaled quant tables, f64
    __shared__ double TR[3][576];      // per-wave transpose buf: (r,k) of blk at blk*72+r*9+k
    __shared__ float  REC[3][8][68];   // reconstructed YCbCr strip (f32), row pad 68

    const int t   = threadIdx.x;
    const int w   = t >> 6;      // channel = wave id (wave-uniform)
    const int l   = t & 63;
    const int blk = l >> 3;      // block within strip (0..7)
    const int rr  = l & 7;       // row within block

    const int b    = blockIdx.x >> 9;   // image index
    const int rem  = blockIdx.x & 511;
    const int row0 = (rem >> 3) << 3;   // strip row * 8
    const int col0 = (rem & 7) << 6;    // strip col * 64

    const size_t plane = 512 * 512;

    // ---- Issue global loads early (my row's 8 px, all 3 planes, float4)
    const float* p = img + (size_t)(b * 3) * plane + (size_t)(row0 + rr) * 512 + col0 + blk * 8;
    float4 R0 = *(const float4*)(p);
    float4 R1 = *(const float4*)(p + 4);
    float4 G0 = *(const float4*)(p + plane);
    float4 G1 = *(const float4*)(p + plane + 4);
    float4 B0 = *(const float4*)(p + 2 * plane);
    float4 B1 = *(const float4*)(p + 2 * plane + 4);

    // ---- Build quant tables in LDS (f64, same arithmetic as passing rounds)
    if (t < 128) {
        int tbl = t >> 6, e = t & 63;
        int q   = quality[0];
        q = q < 1 ? 1 : (q > 100 ? 100 : q);
        double scale = (q < 50) ? (5000.0 / (double)q) : (200.0 - 2.0 * (double)q);
        double base  = tbl ? CHROM_BASE[e] : LUM_BASE[e];
        double v = (base * scale + 50.0) / 100.0;
        QT[t] = fmin(fmax(v, 1.0), 255.0);
    }
    __syncthreads();

    // Exact f64 YCbCr weights (identical expressions to the passing R2 kernel)
    const double W00 =  0.299,   W01 =  0.587,   W02 =  0.114;
    const double W10 = -0.1687,  W11 = -0.3313,  W12 =  0.5;
    const double W20 =  0.5,     W21 = -0.4187,  W22 = -0.0813;

    float rf[8] = {R0.x, R0.y, R0.z, R0.w, R1.x, R1.y, R1.z, R1.w};
    float gf[8] = {G0.x, G0.y, G0.z, G0.w, G1.x, G1.y, G1.z, G1.w};
    float bf[8] = {B0.x, B0.y, B0.z, B0.w, B1.x, B1.y, B1.z, B1.w};

    // ---- Color convert (my channel only), -128
    double row[8];
    #pragma unroll
    for (int k = 0; k < 8; ++k) {
        double rv = (double)rf[k] * 255.0;
        double gv = (double)gf[k] * 255.0;
        double bv = (double)bf[k] * 255.0;
        double v;
        if (w == 0)      v = W00 * rv + W01 * gv + W02 * bv;
        else if (w == 1) v = W10 * rv + W11 * gv + W12 * bv + 128.0;
        else             v = W20 * rv + W21 * gv + W22 * bv + 128.0;
        row[k] = v - 128.0;
    }

    // ---- P1: row @ M^T (A1 row rr) — constants fold, same products/order as R2
    double y[8];
    #pragma unroll
    for (int c = 0; c < 8; ++c) {
        double s = 0.0;
        #pragma unroll
        for (int k = 0; k < 8; ++k)
            s += row[k] * Mc[c][k];
        y[c] = s;
    }

    // ---- Transpose 1 (write my row, read my column)
    {
        double* tb = TR[w] + blk * 72 + rr * 9;
        #pragma unroll
        for (int k = 0; k < 8; ++k) tb[k] = y[k];
    }
    __syncthreads();
    double t1[8], qv[8];
    {
        const double* tb = TR[w] + blk * 72 + rr;
        #pragma unroll
        for (int k = 0; k < 8; ++k) t1[k] = tb[k * 9];
    }
    // My quant column (broadcast-friendly reads)
    const int sel = ((b * 3 + w) < 16) ? 0 : 1;   // reference's flattened-index quirk
    #pragma unroll
    for (int j = 0; j < 8; ++j) qv[j] = QT[(sel << 6) + (j << 3) + rr];

    // ---- P2: column DCT + quantize  tq = rint(dct/q)*q  [identical to R2]
    double wq[8];
    #pragma unroll
    for (int j = 0; j < 8; ++j) {
        double s = 0.0;
        #pragma unroll
        for (int k = 0; k < 8; ++k)
            s += t1[k] * Mc[j][k];
        wq[j] = rint(s / qv[j]) * qv[j];   // round half-to-even, like jnp.round
    }

    // ---- P3: (tq^T row) @ M  [post-cliff; reassociation safe]
    double a3[8];
    #pragma unroll
    for (int j = 0; j < 8; ++j) {
        double s = 0.0;
        #pragma unroll
        for (int k = 0; k < 8; ++k)
            s += wq[k] * Mc[k][j];
        a3[j] = s;
    }

    // ---- Transpose 2
    __syncthreads();   // protect T1 reads before buffer reuse
    {
        double* tb = TR[w] + blk * 72 + rr * 9;
        #pragma unroll
        for (int k = 0; k < 8; ++k) tb[k] = a3[k];
    }
    __syncthreads();
    double t2[8];
    {
        const double* tb = TR[w] + blk * 72 + rr;
        #pragma unroll
        for (int k = 0; k < 8; ++k) t2[k] = tb[k * 9];
    }

    // ---- P4: final column IDCT, +128, stage to f32 LDS (smooth region)
    {
        float o[8];
        #pragma unroll
        for (int i = 0; i < 8; ++i) {
            double s = 0.0;
            #pragma unroll
            for (int k = 0; k < 8; ++k)
                s += t2[k] * Mc[k][i];
            o[i] = (float)(s + 128.0);
        }
        *(float4*)&REC[w][rr][blk * 8]     = make_float4(o[0], o[1], o[2], o[3]);
        *(float4*)&REC[w][rr][blk * 8 + 4] = make_float4(o[4], o[5], o[6], o[7]);
    }
    __syncthreads();

    // ---- Color back (my wave writes plane w), /255, clip, coalesced store
    float4 Y0 = *(const float4*)&REC[0][rr][blk * 8];
    float4 Y1 = *(const float4*)&REC[0][rr][blk * 8 + 4];
    float4 U0 = *(const float4*)&REC[1][rr][blk * 8];
    float4 U1 = *(const float4*)&REC[1][rr][blk * 8 + 4];
    float4 V0 = *(const float4*)&REC[2][rr][blk * 8];
    float4 V1 = *(const float4*)&REC[2][rr][blk * 8 + 4];
    float yv[8] = {Y0.x, Y0.y, Y0.z, Y0.w, Y1.x, Y1.y, Y1.z, Y1.w};
    float uv[8] = {U0.x, U0.y, U0.z, U0.w, U1.x, U1.y, U1.z, U1.w};
    float vv[8] = {V0.x, V0.y, V0.z, V0.w, V1.x, V1.y, V1.z, V1.w};

    float* q0 = out + (size_t)(b * 3 + w) * plane + (size_t)(row0 + rr) * 512 + col0 + blk * 8;
    float o[8];
    #pragma unroll
    for (int k = 0; k < 8; ++k) {
        double yd = (double)yv[k];
        double cb = (double)uv[k] - 128.0;
        double cr = (double)vv[k] - 128.0;
        double v;
        if (w == 0)      v = yd + 1.402 * cr;
        else if (w == 1) v = yd - 0.34414 * cb - 0.71414 * cr;
        else             v = yd + 1.772 * cb;
        o[k] = (float)fmin(fmax(v / 255.0, 0.0), 1.0);
    }
    *(float4*)(q0)     = make_float4(o[0], o[1], o[2], o[3]);
    *(float4*)(q0 + 4) = make_float4(o[4], o[5], o[6], o[7]);
}

extern "C" void kernel_launch(void* const* d_in, const int* in_sizes, int n_in,
                              void* d_out, int out_size, void* d_ws, size_t ws_size,
                              hipStream_t stream) {
    const float* img     = (const float*)d_in[0];
    const int*   quality = (const int*)d_in[1];
    float*       out     = (float*)d_out;
    // 16 images x 64 row-strips x 8 col-strips = 8192 workgroups x 192 threads
    jpeg_fwd<<<8192, 192, 0, stream>>>(img, quality, out);
}

// Round 6
// 114.435 us; speedup vs baseline: 1.8575x; 1.0950x over previous
//
#include <hip/hip_runtime.h>
#include <math.h>

// Correctly-rounded double constants: Cj = cos(j*pi/16), N0 = sqrt(1/8).
#define C1 0.9807852804032304
#define C2 0.9238795325112867
#define C3 0.8314696123025452
#define C4 0.7071067811865476
#define C5 0.5555702330196022
#define C6 0.3826834323650898
#define C7 0.19509032201612825
#define N0 0.35355339059327373

// DCT-II matrix M[k][n] = norm_k * cos(pi/8*(n+0.5)*k), fully compile-time.
static constexpr double Mc[8][8] = {
 {  N0,      N0,      N0,      N0,      N0,      N0,      N0,      N0    },
 {  .5*C1,   .5*C3,   .5*C5,   .5*C7,  -.5*C7,  -.5*C5,  -.5*C3,  -.5*C1 },
 {  .5*C2,   .5*C6,  -.5*C6,  -.5*C2,  -.5*C2,  -.5*C6,   .5*C6,   .5*C2 },
 {  .5*C3,  -.5*C7,  -.5*C1,  -.5*C5,   .5*C5,   .5*C1,   .5*C7,  -.5*C3 },
 {  .5*C4,  -.5*C4,  -.5*C4,   .5*C4,   .5*C4,  -.5*C4,  -.5*C4,   .5*C4 },
 {  .5*C5,  -.5*C1,   .5*C7,   .5*C3,  -.5*C3,  -.5*C7,   .5*C1,  -.5*C5 },
 {  .5*C6,  -.5*C2,   .5*C2,  -.5*C6,  -.5*C6,   .5*C2,  -.5*C2,   .5*C6 },
 {  .5*C7,  -.5*C5,   .5*C3,  -.5*C1,   .5*C1,  -.5*C3,   .5*C5,  -.5*C7 },
};
// f32 copy for the post-quantization (smooth) path.
#define ROWF(r) {(float)Mc[r][0],(float)Mc[r][1],(float)Mc[r][2],(float)Mc[r][3],\
                 (float)Mc[r][4],(float)Mc[r][5],(float)Mc[r][6],(float)Mc[r][7]}
static constexpr float Mcf[8][8] = {ROWF(0),ROWF(1),ROWF(2),ROWF(3),ROWF(4),ROWF(5),ROWF(6),ROWF(7)};

// JPEG base quantization tables (exact integers)
static __device__ const double LUM_BASE[64] = {
 16,11,10,16,24,40,51,61,
 12,12,14,19,26,58,60,55,
 14,13,16,24,40,57,69,56,
 14,17,22,29,51,87,80,62,
 18,22,37,56,68,109,103,77,
 24,35,55,64,81,104,113,92,
 49,64,78,87,103,121,120,101,
 72,92,95,98,112,100,103,99};
static __device__ const double CHROM_BASE[64] = {
 17,18,24,47,99,99,99,99,
 18,21,26,66,99,99,99,99,
 24,26,56,99,99,99,99,99,
 47,66,99,99,99,99,99,99,
 99,99,99,99,99,99,99,99,
 99,99,99,99,99,99,99,99,
 99,99,99,99,99,99,99,99,
 99,99,99,99,99,99,99,99};

// One thread = one ROW of one 8x8 block of one channel (8 f64 in registers).
// Workgroup = 192 threads = 3 waves; wave w = channel w of an 8x64 strip.
// Pre-cliff (DCT+quant) f64, bit-identical to round-5; post-cliff (IDCT,
// color-back) f32. LDS: transpose-1 region (13.8 KB f64) is reused by
// transpose-2 (f32, first half) + REC staging (f32, second half) -> 14.8 KB
// total -> 10 wg/CU.
__global__ __launch_bounds__(192, 2) void jpeg_fwd(const float* __restrict__ img,
                                                   const int* __restrict__ quality,
                                                   float* __restrict__ out)
{
    __shared__ double QT[128];     // [2][8][8] scaled quant tables, f64
    __shared__ double U[1728];     // 13824 B union region
    double* TR1 = U;                       // [3][576] f64  (transpose-1)
    float*  TR2 = (float*)U;               // [3][576] f32  (transpose-2, bytes 0..6912)
    float*  RECf = (float*)U + 1728;       // [3][8][68] f32 (bytes 6912..13440)

    const int t   = threadIdx.x;
    const int w   = t >> 6;      // channel = wave id (wave-uniform)
    const int l   = t & 63;
    const int blk = l >> 3;      // block within strip (0..7)
    const int rr  = l & 7;       // row within block

    const int b    = blockIdx.x >> 9;   // image index
    const int rem  = blockIdx.x & 511;
    const int row0 = (rem >> 3) << 3;   // strip row * 8
    const int col0 = (rem & 7) << 6;    // strip col * 64

    const size_t plane = 512 * 512;

    // ---- Issue global loads early (my row's 8 px, all 3 planes, float4)
    const float* p = img + (size_t)(b * 3) * plane + (size_t)(row0 + rr) * 512 + col0 + blk * 8;
    float4 R0 = *(const float4*)(p);
    float4 R1 = *(const float4*)(p + 4);
    float4 G0 = *(const float4*)(p + plane);
    float4 G1 = *(const float4*)(p + plane + 4);
    float4 B0 = *(const float4*)(p + 2 * plane);
    float4 B1 = *(const float4*)(p + 2 * plane + 4);

    // ---- Build quant tables in LDS (f64, same arithmetic as passing rounds)
    if (t < 128) {
        int tbl = t >> 6, e = t & 63;
        int q   = quality[0];
        q = q < 1 ? 1 : (q > 100 ? 100 : q);
        double scale = (q < 50) ? (5000.0 / (double)q) : (200.0 - 2.0 * (double)q);
        double base  = tbl ? CHROM_BASE[e] : LUM_BASE[e];
        double v = (base * scale + 50.0) / 100.0;
        QT[t] = fmin(fmax(v, 1.0), 255.0);
    }
    __syncthreads();

    // Exact f64 YCbCr weights (identical expressions to the passing R2 kernel)
    const double W00 =  0.299,   W01 =  0.587,   W02 =  0.114;
    const double W10 = -0.1687,  W11 = -0.3313,  W12 =  0.5;
    const double W20 =  0.5,     W21 = -0.4187,  W22 = -0.0813;

    float rf[8] = {R0.x, R0.y, R0.z, R0.w, R1.x, R1.y, R1.z, R1.w};
    float gf[8] = {G0.x, G0.y, G0.z, G0.w, G1.x, G1.y, G1.z, G1.w};
    float bf[8] = {B0.x, B0.y, B0.z, B0.w, B1.x, B1.y, B1.z, B1.w};

    // ---- Color convert (my channel only), -128  [pre-cliff: f64, unchanged]
    double row[8];
    #pragma unroll
    for (int k = 0; k < 8; ++k) {
        double rv = (double)rf[k] * 255.0;
        double gv = (double)gf[k] * 255.0;
        double bv = (double)bf[k] * 255.0;
        double v;
        if (w == 0)      v = W00 * rv + W01 * gv + W02 * bv;
        else if (w == 1) v = W10 * rv + W11 * gv + W12 * bv + 128.0;
        else             v = W20 * rv + W21 * gv + W22 * bv + 128.0;
        row[k] = v - 128.0;
    }

    // ---- P1: row @ M^T  [pre-cliff: f64, unchanged product order]
    double y[8];
    #pragma unroll
    for (int c = 0; c < 8; ++c) {
        double s = 0.0;
        #pragma unroll
        for (int k = 0; k < 8; ++k)
            s += row[k] * Mc[c][k];
        y[c] = s;
    }

    // ---- Transpose 1 (f64, pad-9 layout)
    {
        double* tb = TR1 + w * 576 + blk * 72 + rr * 9;
        #pragma unroll
        for (int k = 0; k < 8; ++k) tb[k] = y[k];
    }
    __syncthreads();
    double t1[8], qv[8];
    {
        const double* tb = TR1 + w * 576 + blk * 72 + rr;
        #pragma unroll
        for (int k = 0; k < 8; ++k) t1[k] = tb[k * 9];
    }
    const int sel = ((b * 3 + w) < 16) ? 0 : 1;   // reference's flattened-index quirk
    #pragma unroll
    for (int j = 0; j < 8; ++j) qv[j] = QT[(sel << 6) + (j << 3) + rr];

    // ---- P2: column DCT + quantize  tq = rint(dct/q)*q  [pre-cliff: unchanged]
    double wq[8];
    #pragma unroll
    for (int j = 0; j < 8; ++j) {
        double s = 0.0;
        #pragma unroll
        for (int k = 0; k < 8; ++k)
            s += t1[k] * Mc[j][k];
        wq[j] = rint(s / qv[j]) * qv[j];   // round half-to-even, like jnp.round
    }

    // ======== post-cliff: f32 from here on ========
    float wqf[8];
    #pragma unroll
    for (int k = 0; k < 8; ++k) wqf[k] = (float)wq[k];

    // ---- P3: (tq^T row) @ M  (f32)
    float a3[8];
    #pragma unroll
    for (int j = 0; j < 8; ++j) {
        float s = 0.0f;
        #pragma unroll
        for (int k = 0; k < 8; ++k)
            s += wqf[k] * Mcf[k][j];
        a3[j] = s;
    }

    // ---- Transpose 2 (f32, pad-9, reuses transpose-1 bytes)
    __syncthreads();   // all TR1 reads complete before TR2 writes
    {
        float* tb = TR2 + w * 576 + blk * 72 + rr * 9;
        #pragma unroll
        for (int k = 0; k < 8; ++k) tb[k] = a3[k];
    }
    __syncthreads();
    float t2[8];
    {
        const float* tb = TR2 + w * 576 + blk * 72 + rr;
        #pragma unroll
        for (int k = 0; k < 8; ++k) t2[k] = tb[k * 9];
    }

    // ---- P4: final column IDCT (f32), +128, stage to REC
    {
        float o[8];
        #pragma unroll
        for (int i = 0; i < 8; ++i) {
            float s = 0.0f;
            #pragma unroll
            for (int k = 0; k < 8; ++k)
                s += t2[k] * Mcf[k][i];
            o[i] = s + 128.0f;
        }
        float* rc = RECf + w * 544 + rr * 68 + blk * 8;
        *(float4*)(rc)     = make_float4(o[0], o[1], o[2], o[3]);
        *(float4*)(rc + 4) = make_float4(o[4], o[5], o[6], o[7]);
    }
    __syncthreads();

    // ---- Color back (f32, my wave writes plane w), /255, clip, coalesced store
    const float* rY = RECf + 0 * 544 + rr * 68 + blk * 8;
    const float* rU = RECf + 1 * 544 + rr * 68 + blk * 8;
    const float* rV = RECf + 2 * 544 + rr * 68 + blk * 8;
    float4 Y0 = *(const float4*)(rY);
    float4 Y1 = *(const float4*)(rY + 4);
    float4 U0 = *(const float4*)(rU);
    float4 U1 = *(const float4*)(rU + 4);
    float4 V0 = *(const float4*)(rV);
    float4 V1 = *(const float4*)(rV + 4);
    float yv[8] = {Y0.x, Y0.y, Y0.z, Y0.w, Y1.x, Y1.y, Y1.z, Y1.w};
    float uv[8] = {U0.x, U0.y, U0.z, U0.w, U1.x, U1.y, U1.z, U1.w};
    float vv[8] = {V0.x, V0.y, V0.z, V0.w, V1.x, V1.y, V1.z, V1.w};

    float* q0 = out + (size_t)(b * 3 + w) * plane + (size_t)(row0 + rr) * 512 + col0 + blk * 8;
    float o[8];
    #pragma unroll
    for (int k = 0; k < 8; ++k) {
        float yd = yv[k];
        float cb = uv[k] - 128.0f;
        float cr = vv[k] - 128.0f;
        float v;
        if (w == 0)      v = yd + 1.402f * cr;
        else if (w == 1) v = yd - 0.34414f * cb - 0.71414f * cr;
        else             v = yd + 1.772f * cb;
        o[k] = fminf(fmaxf(v * (1.0f / 255.0f), 0.0f), 1.0f);
    }
    *(float4*)(q0)     = make_float4(o[0], o[1], o[2], o[3]);
    *(float4*)(q0 + 4) = make_float4(o[4], o[5], o[6], o[7]);
}

extern "C" void kernel_launch(void* const* d_in, const int* in_sizes, int n_in,
                              void* d_out, int out_size, void* d_ws, size_t ws_size,
                              hipStream_t stream) {
    const float* img     = (const float*)d_in[0];
    const int*   quality = (const int*)d_in[1];
    float*       out     = (float*)d_out;
    // 16 images x 64 row-strips x 8 col-strips = 8192 workgroups x 192 threads
    jpeg_fwd<<<8192, 192, 0, stream>>>(img, quality, out);
}